// Round 5
// baseline (261.450 us; speedup 1.0000x reference)
//
#include <hip/hip_runtime.h>
#include <hip/hip_bf16.h>
#include <math.h>

#define B_ 4
#define N_ 256
#define D_ 128
#define H_ 256
#define K_ 8

typedef __attribute__((ext_vector_type(8))) short short8;
typedef __attribute__((ext_vector_type(4))) float f32x4;

__device__ __forceinline__ unsigned short f2bf(float x) {
    union { __hip_bfloat16 h; unsigned short s; } u;
    u.h = __float2bfloat16(x);
    return u.s;
}
__device__ __forceinline__ short f2bfs(float x) { return (short)f2bf(x); }
__device__ __forceinline__ float bf2f(unsigned short b) {
    unsigned v = ((unsigned)b) << 16;
    return __builtin_bit_cast(float, v);
}

// K0 (fused): blocks 0..255: avec/bvec (4 i-rows per block, W1 cols hoisted);
//             blocks 256..383: Wt[h][d] = bf16(W1c[d][h]).
__global__ __launch_bounds__(256) void pre_kernel(
    const float* __restrict__ s, const float* __restrict__ W1,
    const float* __restrict__ b1,
    float* __restrict__ avec, float* __restrict__ bvec,
    unsigned short* __restrict__ Wt)
{
    int blk = blockIdx.x;
    int t = threadIdx.x;
    if (blk < 256) {
        int bi0 = blk * 4;
        __shared__ float s4[4][D_];
        for (int idx = t; idx < 4 * D_; idx += 256) {
            int r = idx >> 7, d = idx & 127;
            s4[r][d] = s[(size_t)(bi0 + r) * D_ + d];
        }
        __syncthreads();
        float aA[4], aB[4];
        float b1v = b1[t];
        #pragma unroll
        for (int r = 0; r < 4; ++r) { aA[r] = b1v; aB[r] = 0.f; }
        for (int d = 0; d < D_; ++d) {
            float wa = W1[(size_t)d * H_ + t];
            float wb = W1[(size_t)(D_ + d) * H_ + t];
            #pragma unroll
            for (int r = 0; r < 4; ++r) {
                aA[r] = fmaf(s4[r][d], wa, aA[r]);
                aB[r] = fmaf(s4[r][d], wb, aB[r]);
            }
        }
        #pragma unroll
        for (int r = 0; r < 4; ++r) {
            avec[(size_t)(bi0 + r) * H_ + t] = aA[r];
            bvec[(size_t)(bi0 + r) * H_ + t] = aB[r];
        }
    } else {
        int e = (blk - 256) * 256 + t;     // 32768 elements
        int h = e >> 7, d = e & 127;
        Wt[e] = f2bf(W1[(size_t)(2 * D_ + d) * H_ + h]);
    }
}

// K1: approx scores. Block = (b,i), 512 thr = 8 waves = (jg 0..3) x (hg 0..1).
// (Unchanged from R4 — passed.)
__global__ __launch_bounds__(512, 2) void approx_scores(
    const float* __restrict__ s, const unsigned short* __restrict__ Wt,
    const float* __restrict__ W2, const float* __restrict__ b2,
    const float* __restrict__ avec, const float* __restrict__ bvec,
    unsigned short* __restrict__ ascu)
{
    int bi = blockIdx.x;
    int b  = bi >> 8;
    int t = threadIdx.x;
    int lane = t & 63;
    int wid = __builtin_amdgcn_readfirstlane(t >> 6);
    int jg = wid & 3, hg = wid >> 2;
    int l15 = lane & 15, quad = lane >> 4;

    __shared__ __align__(16) unsigned char lds_raw[65536];
    short* Pl = (short*)lds_raw;
    float* Pf = (float*)lds_raw;

    {
        int d0 = (t & 15) * 8;
        const float* siP = s + (size_t)bi * D_ + d0;
        float4 si0 = *(const float4*)siP;
        float4 si1 = *(const float4*)(siP + 4);
        int rbase = t >> 4;
        int pc = (t & 15) ^ (rbase & 15);
        #pragma unroll
        for (int k = 0; k < 8; ++k) {
            int row = rbase + 32 * k;
            const float* sjP = s + ((size_t)(b * N_ + row)) * D_ + d0;
            float4 a0 = *(const float4*)sjP;
            float4 a1 = *(const float4*)(sjP + 4);
            short8 v;
            v[0] = f2bfs(a0.x * si0.x); v[1] = f2bfs(a0.y * si0.y);
            v[2] = f2bfs(a0.z * si0.z); v[3] = f2bfs(a0.w * si0.w);
            v[4] = f2bfs(a1.x * si1.x); v[5] = f2bfs(a1.y * si1.y);
            v[6] = f2bfs(a1.z * si1.z); v[7] = f2bfs(a1.w * si1.w);
            *(short8*)&Pl[row * 128 + pc * 8] = v;
        }
    }
    float av[8], w2v[8];
    #pragma unroll
    for (int ni = 0; ni < 8; ++ni) {
        int h = hg * 128 + ni * 16 + l15;
        av[ni]  = avec[(size_t)bi * H_ + h];
        w2v[ni] = W2[h];
    }
    __syncthreads();

    float rsAll[4][4];
    #pragma unroll
    for (int mi = 0; mi < 4; ++mi)
        #pragma unroll
        for (int r = 0; r < 4; ++r) rsAll[mi][r] = 0.f;

    for (int half = 0; half < 2; ++half) {
        short8 Bf[4][4];
        #pragma unroll
        for (int nni = 0; nni < 4; ++nni) {
            int h = hg * 128 + half * 64 + nni * 16 + l15;
            #pragma unroll
            for (int dk = 0; dk < 4; ++dk)
                Bf[nni][dk] = *(const short8*)(Wt + (size_t)h * D_ + dk * 32 + quad * 8);
        }
        #pragma unroll 1
        for (int mi = 0; mi < 4; ++mi) {
            int jb = jg * 64 + mi * 16;
            short8 Af[4];
            #pragma unroll
            for (int dk = 0; dk < 4; ++dk) {
                int pcc = (4 * dk + quad) ^ l15;
                Af[dk] = *(const short8*)&Pl[(jb + l15) * 128 + pcc * 8];
            }
            float bv[4][4];
            #pragma unroll
            for (int nni = 0; nni < 4; ++nni) {
                int h = hg * 128 + half * 64 + nni * 16 + l15;
                #pragma unroll
                for (int r = 0; r < 4; ++r)
                    bv[nni][r] = bvec[((size_t)(b * N_ + jb + quad * 4 + r)) * H_ + h];
            }
            f32x4 acc[4];
            #pragma unroll
            for (int nni = 0; nni < 4; ++nni)
                acc[nni] = (f32x4){0.f, 0.f, 0.f, 0.f};
            #pragma unroll
            for (int dk = 0; dk < 4; ++dk)
                #pragma unroll
                for (int nni = 0; nni < 4; ++nni)
                    acc[nni] = __builtin_amdgcn_mfma_f32_16x16x32_bf16(
                        Af[dk], Bf[nni][dk], acc[nni], 0, 0, 0);
            #pragma unroll
            for (int r = 0; r < 4; ++r) {
                float rs = rsAll[mi][r];
                #pragma unroll
                for (int nni = 0; nni < 4; ++nni) {
                    int ni = half * 4 + nni;
                    float z = acc[nni][r] + av[ni] + bv[nni][r];
                    rs = fmaf(fmaxf(z, 0.f), w2v[ni], rs);
                }
                rsAll[mi][r] = rs;
            }
        }
    }
    __syncthreads();
    #pragma unroll
    for (int mi = 0; mi < 4; ++mi)
        #pragma unroll
        for (int r = 0; r < 4; ++r) {
            float v = rsAll[mi][r];
            v += __shfl_xor(v, 1); v += __shfl_xor(v, 2);
            v += __shfl_xor(v, 4); v += __shfl_xor(v, 8);
            if (l15 == 0)
                Pf[hg * 256 + jg * 64 + mi * 16 + quad * 4 + r] = v;
        }
    __syncthreads();
    if (t < 256) {
        float v = Pf[t] + Pf[256 + t] + b2[0];
        ascu[(size_t)bi * N_ + t] = f2bf(v);
    }
}

// K2: per block = 4 rows, 1024 threads = 16 waves.
// wave = (row r, h-slice g*64); lane = (cand c = lane>>2, h-sub ks = lane&3).
// Each lane: 16 h in registers, per-lane coalesced float4 W loads (no s_load
// serial chain), 16 waves/CU for latency hiding.
#define PADP 132   // c-stride mod 32 banks = 4c -> only c<->c+8 alias (2-way, free)
__global__ __launch_bounds__(1024, 4) void finalize_kernel(
    const float* __restrict__ s, const float* __restrict__ W1,
    const float* __restrict__ W2, const float* __restrict__ b2,
    const float* __restrict__ avec, const float* __restrict__ bvec,
    const unsigned short* __restrict__ ascu,
    float* __restrict__ ctx, float* __restrict__ gate, float* __restrict__ w)
{
    int bi0 = blockIdx.x * 4;          // 256 blocks
    int b = bi0 >> 8;
    int t = threadIdx.x;               // 0..1023
    int lane = t & 63;
    int wid = __builtin_amdgcn_readfirstlane(t >> 6);  // 0..15
    int r = wid >> 2, g = wid & 3;     // wave: row, h-slice
    int c = lane >> 2, ks = lane & 3;  // lane: cand, h-sub

    __shared__ float asc[4][N_];
    __shared__ int cand[4][16];
    __shared__ __align__(16) float Pl2[64 * PADP];   // 33792 B
    __shared__ float part[4][4][16];   // [r][g][c]
    __shared__ float rsc[4][16];
    __shared__ int sel8[4][8];

    // load approx scores: 1024 threads -> exactly one each
    {
        int tr = t >> 8, jj = t & 255;
        asc[tr][jj] = bf2f(ascu[(size_t)(bi0 + tr) * N_ + jj]);
    }
    __syncthreads();

    // top-16 per row: thread t ranks its own (row, j); asc reads are
    // wave-uniform broadcasts (tr uniform per wave)
    {
        int tr = t >> 8, jj = t & 255;
        float my = asc[tr][jj];
        int rank = 0;
        #pragma unroll 8
        for (int j2 = 0; j2 < N_; ++j2) {
            float o = asc[tr][j2];
            rank += (o > my) || (o == my && j2 < jj);
        }
        if (rank < 16) cand[tr][rank] = jj;
    }
    __syncthreads();

    // build P rows: 64 pairs x 128 d = 2048 float4-chunks, 2 per thread
    for (int e = t; e < 2048; e += 1024) {
        int p = e >> 5, dc = e & 31;
        int rr = p >> 4, cc = p & 15;
        int j = cand[rr][cc];
        float4 sj = *(const float4*)(s + ((size_t)(b * N_ + j)) * D_ + dc * 4);
        float4 si = *(const float4*)(s + ((size_t)(bi0 + rr)) * D_ + dc * 4);
        float4 pv;
        pv.x = si.x * sj.x; pv.y = si.y * sj.y;
        pv.z = si.z * sj.z; pv.w = si.w * sj.w;
        *(float4*)&Pl2[p * PADP + dc * 4] = pv;
    }
    __syncthreads();

    // exact fp32 rescore: lane accumulates 16 h
    {
        int j = cand[r][c];
        int h0 = g * 64 + ks * 16;
        const float* Wc = W1 + (size_t)2 * D_ * H_;          // W1c[d][h]
        const float* av = avec + (size_t)(bi0 + r) * H_ + h0;
        const float* bvp = bvec + ((size_t)(b * N_ + j)) * H_ + h0;
        float acc[16];
        #pragma unroll
        for (int m4 = 0; m4 < 4; ++m4) {
            float4 a4 = *(const float4*)(av + m4 * 4);
            float4 b4 = *(const float4*)(bvp + m4 * 4);
            acc[m4 * 4 + 0] = a4.x + b4.x;
            acc[m4 * 4 + 1] = a4.y + b4.y;
            acc[m4 * 4 + 2] = a4.z + b4.z;
            acc[m4 * 4 + 3] = a4.w + b4.w;
        }
        const float* Prow = &Pl2[(r * 16 + c) * PADP];
        for (int d = 0; d < D_; d += 4) {
            float4 p4 = *(const float4*)&Prow[d];
            #pragma unroll
            for (int dd = 0; dd < 4; ++dd) {
                float p = (dd == 0) ? p4.x : (dd == 1) ? p4.y : (dd == 2) ? p4.z : p4.w;
                const float* wrow = Wc + (size_t)(d + dd) * H_ + h0;
                float wv[16];
                *(float4*)&wv[0]  = ((const float4*)wrow)[0];
                *(float4*)&wv[4]  = ((const float4*)wrow)[1];
                *(float4*)&wv[8]  = ((const float4*)wrow)[2];
                *(float4*)&wv[12] = ((const float4*)wrow)[3];
                #pragma unroll
                for (int m = 0; m < 16; ++m)
                    acc[m] = fmaf(p, wv[m], acc[m]);
            }
        }
        float w2v[16];
        *(float4*)&w2v[0]  = *(const float4*)(W2 + h0);
        *(float4*)&w2v[4]  = *(const float4*)(W2 + h0 + 4);
        *(float4*)&w2v[8]  = *(const float4*)(W2 + h0 + 8);
        *(float4*)&w2v[12] = *(const float4*)(W2 + h0 + 12);
        float rs = 0.f;
        #pragma unroll
        for (int m = 0; m < 16; ++m)
            rs = fmaf(fmaxf(acc[m], 0.f), w2v[m], rs);
        rs += __shfl_xor(rs, 1);
        rs += __shfl_xor(rs, 2);
        if (ks == 0) part[r][g][c] = rs;
    }
    __syncthreads();
    if (t < 64) {
        int rr = t >> 4, cc = t & 15;
        rsc[rr][cc] = part[rr][0][cc] + part[rr][1][cc]
                    + part[rr][2][cc] + part[rr][3][cc] + b2[0];
    }
    __syncthreads();

    // top-8 among 16 exact scores, tiebreak smaller original index
    if (t < 64) {
        int rr = t >> 4, cc = t & 15;
        float my = rsc[rr][cc]; int myj = cand[rr][cc];
        int rank = 0;
        #pragma unroll
        for (int c2 = 0; c2 < 16; ++c2) {
            float o = rsc[rr][c2]; int oj = cand[rr][c2];
            rank += (o > my) || (o == my && oj < myj);
        }
        if (rank < 8) sel8[rr][rank] = myj;
    }
    __syncthreads();

    // gate / w: 1024 threads -> one element each
    {
        int rr = t >> 8, jj = t & 255;
        float gv = 0.f;
        #pragma unroll
        for (int m = 0; m < 8; ++m)
            gv = (jj == sel8[rr][m]) ? 1.f : gv;
        gate[(size_t)(bi0 + rr) * N_ + jj] = gv;
        w[(size_t)(bi0 + rr) * N_ + jj]    = gv * 0.125f;
    }
    // ctx: 4 rows x 128 d = 512 elements
    if (t < 512) {
        int rr = t >> 7, d = t & 127;
        float a = 0.f;
        #pragma unroll
        for (int m = 0; m < 8; ++m)
            a += s[((size_t)(b * N_ + sel8[rr][m])) * D_ + d];
        ctx[(size_t)(bi0 + rr) * D_ + d] = a * 0.125f;
    }
}

extern "C" void kernel_launch(void* const* d_in, const int* in_sizes, int n_in,
                              void* d_out, int out_size, void* d_ws, size_t ws_size,
                              hipStream_t stream)
{
    const float* s  = (const float*)d_in[0];
    const float* W1 = (const float*)d_in[1];
    const float* b1 = (const float*)d_in[2];
    const float* W2 = (const float*)d_in[3];
    const float* b2 = (const float*)d_in[4];

    float* avec = (float*)d_ws;                                           // 262144 f
    float* bvec = avec + (size_t)B_ * N_ * H_;                            // 262144 f
    unsigned short* ascu = (unsigned short*)(bvec + (size_t)B_ * N_ * H_);// 262144 us
    unsigned short* Wtu  = ascu + (size_t)B_ * N_ * N_;                   // 32768 us

    float* ctx  = (float*)d_out;
    float* gate = ctx + (size_t)B_ * N_ * D_;
    float* wout = gate + (size_t)B_ * N_ * N_;

    pre_kernel<<<384, 256, 0, stream>>>(s, W1, b1, avec, bvec, Wtu);
    approx_scores<<<B_ * N_, 512, 0, stream>>>(s, Wtu, W2, b2, avec, bvec, ascu);
    finalize_kernel<<<B_ * N_ / 4, 1024, 0, stream>>>(s, W1, W2, b2, avec, bvec, ascu,
                                                      ctx, gate, wout);
}

// Round 6
// 194.154 us; speedup vs baseline: 1.3466x; 1.3466x over previous
//
#include <hip/hip_runtime.h>
#include <hip/hip_bf16.h>
#include <math.h>

#define B_ 4
#define N_ 256
#define D_ 128
#define H_ 256
#define K_ 8

typedef __attribute__((ext_vector_type(8))) short short8;
typedef __attribute__((ext_vector_type(4))) float f32x4;

__device__ __forceinline__ unsigned short f2bf(float x) {
    union { __hip_bfloat16 h; unsigned short s; } u;
    u.h = __float2bfloat16(x);
    return u.s;
}
__device__ __forceinline__ short f2bfs(float x) { return (short)f2bf(x); }
__device__ __forceinline__ float bf2f(unsigned short b) {
    unsigned v = ((unsigned)b) << 16;
    return __builtin_bit_cast(float, v);
}

// K0 (fused): blocks 0..255: avec/bvec (4 i-rows per block, W1 cols hoisted);
//             blocks 256..383: Wt[h][d] = bf16(W1c[d][h]).   (Unchanged — passed.)
__global__ __launch_bounds__(256) void pre_kernel(
    const float* __restrict__ s, const float* __restrict__ W1,
    const float* __restrict__ b1,
    float* __restrict__ avec, float* __restrict__ bvec,
    unsigned short* __restrict__ Wt)
{
    int blk = blockIdx.x;
    int t = threadIdx.x;
    if (blk < 256) {
        int bi0 = blk * 4;
        __shared__ float s4[4][D_];
        for (int idx = t; idx < 4 * D_; idx += 256) {
            int r = idx >> 7, d = idx & 127;
            s4[r][d] = s[(size_t)(bi0 + r) * D_ + d];
        }
        __syncthreads();
        float aA[4], aB[4];
        float b1v = b1[t];
        #pragma unroll
        for (int r = 0; r < 4; ++r) { aA[r] = b1v; aB[r] = 0.f; }
        for (int d = 0; d < D_; ++d) {
            float wa = W1[(size_t)d * H_ + t];
            float wb = W1[(size_t)(D_ + d) * H_ + t];
            #pragma unroll
            for (int r = 0; r < 4; ++r) {
                aA[r] = fmaf(s4[r][d], wa, aA[r]);
                aB[r] = fmaf(s4[r][d], wb, aB[r]);
            }
        }
        #pragma unroll
        for (int r = 0; r < 4; ++r) {
            avec[(size_t)(bi0 + r) * H_ + t] = aA[r];
            bvec[(size_t)(bi0 + r) * H_ + t] = aB[r];
        }
    } else {
        int e = (blk - 256) * 256 + t;
        int h = e >> 7, d = e & 127;
        Wt[e] = f2bf(W1[(size_t)(2 * D_ + d) * H_ + h]);
    }
}

// K1: approx scores via bf16 MFMA. (Unchanged — passed.)
__global__ __launch_bounds__(512, 2) void approx_scores(
    const float* __restrict__ s, const unsigned short* __restrict__ Wt,
    const float* __restrict__ W2, const float* __restrict__ b2,
    const float* __restrict__ avec, const float* __restrict__ bvec,
    unsigned short* __restrict__ ascu)
{
    int bi = blockIdx.x;
    int b  = bi >> 8;
    int t = threadIdx.x;
    int lane = t & 63;
    int wid = __builtin_amdgcn_readfirstlane(t >> 6);
    int jg = wid & 3, hg = wid >> 2;
    int l15 = lane & 15, quad = lane >> 4;

    __shared__ __align__(16) unsigned char lds_raw[65536];
    short* Pl = (short*)lds_raw;
    float* Pf = (float*)lds_raw;

    {
        int d0 = (t & 15) * 8;
        const float* siP = s + (size_t)bi * D_ + d0;
        float4 si0 = *(const float4*)siP;
        float4 si1 = *(const float4*)(siP + 4);
        int rbase = t >> 4;
        int pc = (t & 15) ^ (rbase & 15);
        #pragma unroll
        for (int k = 0; k < 8; ++k) {
            int row = rbase + 32 * k;
            const float* sjP = s + ((size_t)(b * N_ + row)) * D_ + d0;
            float4 a0 = *(const float4*)sjP;
            float4 a1 = *(const float4*)(sjP + 4);
            short8 v;
            v[0] = f2bfs(a0.x * si0.x); v[1] = f2bfs(a0.y * si0.y);
            v[2] = f2bfs(a0.z * si0.z); v[3] = f2bfs(a0.w * si0.w);
            v[4] = f2bfs(a1.x * si1.x); v[5] = f2bfs(a1.y * si1.y);
            v[6] = f2bfs(a1.z * si1.z); v[7] = f2bfs(a1.w * si1.w);
            *(short8*)&Pl[row * 128 + pc * 8] = v;
        }
    }
    float av[8], w2v[8];
    #pragma unroll
    for (int ni = 0; ni < 8; ++ni) {
        int h = hg * 128 + ni * 16 + l15;
        av[ni]  = avec[(size_t)bi * H_ + h];
        w2v[ni] = W2[h];
    }
    __syncthreads();

    float rsAll[4][4];
    #pragma unroll
    for (int mi = 0; mi < 4; ++mi)
        #pragma unroll
        for (int r = 0; r < 4; ++r) rsAll[mi][r] = 0.f;

    for (int half = 0; half < 2; ++half) {
        short8 Bf[4][4];
        #pragma unroll
        for (int nni = 0; nni < 4; ++nni) {
            int h = hg * 128 + half * 64 + nni * 16 + l15;
            #pragma unroll
            for (int dk = 0; dk < 4; ++dk)
                Bf[nni][dk] = *(const short8*)(Wt + (size_t)h * D_ + dk * 32 + quad * 8);
        }
        #pragma unroll 1
        for (int mi = 0; mi < 4; ++mi) {
            int jb = jg * 64 + mi * 16;
            short8 Af[4];
            #pragma unroll
            for (int dk = 0; dk < 4; ++dk) {
                int pcc = (4 * dk + quad) ^ l15;
                Af[dk] = *(const short8*)&Pl[(jb + l15) * 128 + pcc * 8];
            }
            float bv[4][4];
            #pragma unroll
            for (int nni = 0; nni < 4; ++nni) {
                int h = hg * 128 + half * 64 + nni * 16 + l15;
                #pragma unroll
                for (int r = 0; r < 4; ++r)
                    bv[nni][r] = bvec[((size_t)(b * N_ + jb + quad * 4 + r)) * H_ + h];
            }
            f32x4 acc[4];
            #pragma unroll
            for (int nni = 0; nni < 4; ++nni)
                acc[nni] = (f32x4){0.f, 0.f, 0.f, 0.f};
            #pragma unroll
            for (int dk = 0; dk < 4; ++dk)
                #pragma unroll
                for (int nni = 0; nni < 4; ++nni)
                    acc[nni] = __builtin_amdgcn_mfma_f32_16x16x32_bf16(
                        Af[dk], Bf[nni][dk], acc[nni], 0, 0, 0);
            #pragma unroll
            for (int r = 0; r < 4; ++r) {
                float rs = rsAll[mi][r];
                #pragma unroll
                for (int nni = 0; nni < 4; ++nni) {
                    int ni = half * 4 + nni;
                    float z = acc[nni][r] + av[ni] + bv[nni][r];
                    rs = fmaf(fmaxf(z, 0.f), w2v[ni], rs);
                }
                rsAll[mi][r] = rs;
            }
        }
    }
    __syncthreads();
    #pragma unroll
    for (int mi = 0; mi < 4; ++mi)
        #pragma unroll
        for (int r = 0; r < 4; ++r) {
            float v = rsAll[mi][r];
            v += __shfl_xor(v, 1); v += __shfl_xor(v, 2);
            v += __shfl_xor(v, 4); v += __shfl_xor(v, 8);
            if (l15 == 0)
                Pf[hg * 256 + jg * 64 + mi * 16 + quad * 4 + r] = v;
        }
    __syncthreads();
    if (t < 256) {
        float v = Pf[t] + Pf[256 + t] + b2[0];
        ascu[(size_t)bi * N_ + t] = f2bf(v);
    }
}

// K2 v3: rescore as a register-blocked fp32 GEMM.
// Block = 4 rows = 64 pairs, 256 threads. Thread (pg=t&15, hg=t>>4) owns
// acc[4 pairs][16 h] (64 VGPR). Pt[d][pair] transposed in LDS (b128 -> 4
// pairs' P). W staged via LDS in 16-d chunks, register-prefetched. Wl reads
// are wave-broadcast (hg uniform-4 per wave); Pt reads 2-way (free).
#define DC 16
__global__ __launch_bounds__(256) void finalize_kernel(
    const float* __restrict__ s, const float* __restrict__ W1,
    const float* __restrict__ W2, const float* __restrict__ b2,
    const float* __restrict__ avec, const float* __restrict__ bvec,
    const unsigned short* __restrict__ ascu,
    float* __restrict__ ctx, float* __restrict__ gate, float* __restrict__ w)
{
    int bi0 = blockIdx.x * 4;          // 256 blocks
    int b = bi0 >> 8;
    int t = threadIdx.x;
    int lane = t & 63;
    int g = __builtin_amdgcn_readfirstlane(t >> 6);

    __shared__ float asc[4][N_];                    // 4 KB
    __shared__ int cand[4][16];
    __shared__ __align__(16) float Pt[D_][64];      // 32 KB  [d][pair]
    __shared__ __align__(16) float Wl[DC][H_];      // 16 KB  [d-in-chunk][h]
    __shared__ float part[64][17];                  // 4.25 KB [pair][hg]
    __shared__ float rsc[4][16];
    __shared__ int sel8[4][8];

    // --- approx scores + top-16 per row (wave g owns row g) ---
    for (int e = t; e < 4 * N_; e += 256) {
        int r = e >> 8, j = e & 255;
        asc[r][j] = bf2f(ascu[(size_t)(bi0 + r) * N_ + j]);
    }
    __syncthreads();
    {
        int r = g;
        for (int m = 0; m < 4; ++m) {
            int jj = m * 64 + lane;
            float my = asc[r][jj];
            int rank = 0;
            #pragma unroll 8
            for (int j2 = 0; j2 < N_; ++j2) {
                float o = asc[r][j2];
                rank += (o > my) || (o == my && j2 < jj);
            }
            if (rank < 16) cand[r][rank] = jj;
        }
    }
    __syncthreads();

    const float* Wc = W1 + (size_t)2 * D_ * H_;     // W1c[d][h], row stride H_

    // prefetch W chunk 0 while building Pt
    float4 wpre[4];
    #pragma unroll
    for (int k = 0; k < 4; ++k) {
        int q = t + 256 * k;                        // 0..1023
        int dd = q >> 6, hh = (q & 63) * 4;
        wpre[k] = *(const float4*)(Wc + (size_t)dd * H_ + hh);
    }

    // build Pt[d][pair] (transposed, conflict-free writes)
    for (int e = t; e < 2048; e += 256) {
        int p = e & 63, dq = e >> 6;                // dq 0..31 -> d = 4dq..4dq+3
        int r = p >> 4, c = p & 15;
        int j = cand[r][c];
        float4 sj = *(const float4*)(s + ((size_t)(b * N_ + j)) * D_ + dq * 4);
        float4 si = *(const float4*)(s + ((size_t)(bi0 + r)) * D_ + dq * 4);
        Pt[dq * 4 + 0][p] = si.x * sj.x;
        Pt[dq * 4 + 1][p] = si.y * sj.y;
        Pt[dq * 4 + 2][p] = si.z * sj.z;
        Pt[dq * 4 + 3][p] = si.w * sj.w;
    }

    // acc init: exact fp32 a_i[h] + b_j[h]
    int pg = t & 15, hg = t >> 4;
    int h0 = hg * 16;
    float acc[4][16];
    #pragma unroll
    for (int pp = 0; pp < 4; ++pp) {
        int p = pg * 4 + pp;
        int r = p >> 4, c = p & 15;
        int j = cand[r][c];
        const float* av = avec + (size_t)(bi0 + r) * H_ + h0;
        const float* bv = bvec + ((size_t)(b * N_ + j)) * H_ + h0;
        #pragma unroll
        for (int m4 = 0; m4 < 4; ++m4) {
            float4 a4 = *(const float4*)(av + m4 * 4);
            float4 b4 = *(const float4*)(bv + m4 * 4);
            acc[pp][m4 * 4 + 0] = a4.x + b4.x;
            acc[pp][m4 * 4 + 1] = a4.y + b4.y;
            acc[pp][m4 * 4 + 2] = a4.z + b4.z;
            acc[pp][m4 * 4 + 3] = a4.w + b4.w;
        }
    }
    __syncthreads();                                // Pt built

    // --- K-chunked GEMM: acc[pp][m] += Pt[d][4pg+pp] * W[d][h0+m] ---
    for (int ch = 0; ch < 8; ++ch) {
        #pragma unroll
        for (int k = 0; k < 4; ++k) {
            int q = t + 256 * k;
            int dd = q >> 6, hh = (q & 63) * 4;
            *(float4*)&Wl[dd][hh] = wpre[k];
        }
        __syncthreads();
        if (ch < 7) {
            int d0n = (ch + 1) * DC;
            #pragma unroll
            for (int k = 0; k < 4; ++k) {
                int q = t + 256 * k;
                int dd = q >> 6, hh = (q & 63) * 4;
                wpre[k] = *(const float4*)(Wc + (size_t)(d0n + dd) * H_ + hh);
            }
        }
        int d0 = ch * DC;
        #pragma unroll
        for (int d = 0; d < DC; ++d) {
            float4 pv = *(const float4*)&Pt[d0 + d][pg * 4];
            float wv[16];
            *(float4*)&wv[0]  = *(const float4*)&Wl[d][h0];
            *(float4*)&wv[4]  = *(const float4*)&Wl[d][h0 + 4];
            *(float4*)&wv[8]  = *(const float4*)&Wl[d][h0 + 8];
            *(float4*)&wv[12] = *(const float4*)&Wl[d][h0 + 12];
            #pragma unroll
            for (int m = 0; m < 16; ++m) {
                acc[0][m] = fmaf(pv.x, wv[m], acc[0][m]);
                acc[1][m] = fmaf(pv.y, wv[m], acc[1][m]);
                acc[2][m] = fmaf(pv.z, wv[m], acc[2][m]);
                acc[3][m] = fmaf(pv.w, wv[m], acc[3][m]);
            }
        }
        __syncthreads();
    }

    // --- epilogue: relu * W2, reduce over hg groups ---
    {
        float w2v[16];
        *(float4*)&w2v[0]  = *(const float4*)(W2 + h0);
        *(float4*)&w2v[4]  = *(const float4*)(W2 + h0 + 4);
        *(float4*)&w2v[8]  = *(const float4*)(W2 + h0 + 8);
        *(float4*)&w2v[12] = *(const float4*)(W2 + h0 + 12);
        #pragma unroll
        for (int pp = 0; pp < 4; ++pp) {
            float sc = 0.f;
            #pragma unroll
            for (int m = 0; m < 16; ++m)
                sc = fmaf(fmaxf(acc[pp][m], 0.f), w2v[m], sc);
            part[pg * 4 + pp][hg] = sc;
        }
    }
    __syncthreads();
    if (t < 64) {
        float sum = b2[0];
        #pragma unroll
        for (int m = 0; m < 16; ++m) sum += part[t][m];
        rsc[t >> 4][t & 15] = sum;
    }
    __syncthreads();

    // top-8 among 16 exact scores, tiebreak smaller original index
    if (t < 64) {
        int rr = t >> 4, cc = t & 15;
        float my = rsc[rr][cc]; int myj = cand[rr][cc];
        int rank = 0;
        #pragma unroll
        for (int c2 = 0; c2 < 16; ++c2) {
            float o = rsc[rr][c2]; int oj = cand[rr][c2];
            rank += (o > my) || (o == my && oj < myj);
        }
        if (rank < 8) sel8[rr][rank] = myj;
    }
    __syncthreads();

    // gate / w
    for (int e = t; e < 4 * N_; e += 256) {
        int rr = e >> 8, jj = e & 255;
        float gv = 0.f;
        #pragma unroll
        for (int m = 0; m < 8; ++m)
            gv = (jj == sel8[rr][m]) ? 1.f : gv;
        gate[(size_t)(bi0 + rr) * N_ + jj] = gv;
        w[(size_t)(bi0 + rr) * N_ + jj]    = gv * 0.125f;
    }
    // ctx
    for (int e = t; e < 4 * D_; e += 256) {
        int rr = e >> 7, d = e & 127;
        float a = 0.f;
        #pragma unroll
        for (int m = 0; m < 8; ++m)
            a += s[((size_t)(b * N_ + sel8[rr][m])) * D_ + d];
        ctx[(size_t)(bi0 + rr) * D_ + d] = a * 0.125f;
    }
}

extern "C" void kernel_launch(void* const* d_in, const int* in_sizes, int n_in,
                              void* d_out, int out_size, void* d_ws, size_t ws_size,
                              hipStream_t stream)
{
    const float* s  = (const float*)d_in[0];
    const float* W1 = (const float*)d_in[1];
    const float* b1 = (const float*)d_in[2];
    const float* W2 = (const float*)d_in[3];
    const float* b2 = (const float*)d_in[4];

    float* avec = (float*)d_ws;                                           // 262144 f
    float* bvec = avec + (size_t)B_ * N_ * H_;                            // 262144 f
    unsigned short* ascu = (unsigned short*)(bvec + (size_t)B_ * N_ * H_);// 262144 us
    unsigned short* Wtu  = ascu + (size_t)B_ * N_ * N_;                   // 32768 us

    float* ctx  = (float*)d_out;
    float* gate = ctx + (size_t)B_ * N_ * D_;
    float* wout = gate + (size_t)B_ * N_ * N_;

    pre_kernel<<<384, 256, 0, stream>>>(s, W1, b1, avec, bvec, Wtu);
    approx_scores<<<B_ * N_, 512, 0, stream>>>(s, Wtu, W2, b2, avec, bvec, ascu);
    finalize_kernel<<<B_ * N_ / 4, 256, 0, stream>>>(s, W1, W2, b2, avec, bvec, ascu,
                                                     ctx, gate, wout);
}

// Round 7
// 173.134 us; speedup vs baseline: 1.5101x; 1.1214x over previous
//
#include <hip/hip_runtime.h>
#include <hip/hip_bf16.h>
#include <math.h>

#define B_ 4
#define N_ 256
#define D_ 128
#define H_ 256
#define K_ 8

typedef __attribute__((ext_vector_type(8))) short short8;
typedef __attribute__((ext_vector_type(4))) float f32x4;

__device__ __forceinline__ unsigned short f2bf(float x) {
    union { __hip_bfloat16 h; unsigned short s; } u;
    u.h = __float2bfloat16(x);
    return u.s;
}
__device__ __forceinline__ short f2bfs(float x) { return (short)f2bf(x); }
__device__ __forceinline__ float bf2f(unsigned short b) {
    unsigned v = ((unsigned)b) << 16;
    return __builtin_bit_cast(float, v);
}

// K0 (fused): blocks 0..255: avec/bvec; blocks 256..383: Wt transpose. (Unchanged.)
__global__ __launch_bounds__(256) void pre_kernel(
    const float* __restrict__ s, const float* __restrict__ W1,
    const float* __restrict__ b1,
    float* __restrict__ avec, float* __restrict__ bvec,
    unsigned short* __restrict__ Wt)
{
    int blk = blockIdx.x;
    int t = threadIdx.x;
    if (blk < 256) {
        int bi0 = blk * 4;
        __shared__ float s4[4][D_];
        for (int idx = t; idx < 4 * D_; idx += 256) {
            int r = idx >> 7, d = idx & 127;
            s4[r][d] = s[(size_t)(bi0 + r) * D_ + d];
        }
        __syncthreads();
        float aA[4], aB[4];
        float b1v = b1[t];
        #pragma unroll
        for (int r = 0; r < 4; ++r) { aA[r] = b1v; aB[r] = 0.f; }
        for (int d = 0; d < D_; ++d) {
            float wa = W1[(size_t)d * H_ + t];
            float wb = W1[(size_t)(D_ + d) * H_ + t];
            #pragma unroll
            for (int r = 0; r < 4; ++r) {
                aA[r] = fmaf(s4[r][d], wa, aA[r]);
                aB[r] = fmaf(s4[r][d], wb, aB[r]);
            }
        }
        #pragma unroll
        for (int r = 0; r < 4; ++r) {
            avec[(size_t)(bi0 + r) * H_ + t] = aA[r];
            bvec[(size_t)(bi0 + r) * H_ + t] = aB[r];
        }
    } else {
        int e = (blk - 256) * 256 + t;
        int h = e >> 7, d = e & 127;
        Wt[e] = f2bf(W1[(size_t)(2 * D_ + d) * H_ + h]);
    }
}

// K1: approx scores via bf16 MFMA. (Unchanged — passed.)
__global__ __launch_bounds__(512, 2) void approx_scores(
    const float* __restrict__ s, const unsigned short* __restrict__ Wt,
    const float* __restrict__ W2, const float* __restrict__ b2,
    const float* __restrict__ avec, const float* __restrict__ bvec,
    unsigned short* __restrict__ ascu)
{
    int bi = blockIdx.x;
    int b  = bi >> 8;
    int t = threadIdx.x;
    int lane = t & 63;
    int wid = __builtin_amdgcn_readfirstlane(t >> 6);
    int jg = wid & 3, hg = wid >> 2;
    int l15 = lane & 15, quad = lane >> 4;

    __shared__ __align__(16) unsigned char lds_raw[65536];
    short* Pl = (short*)lds_raw;
    float* Pf = (float*)lds_raw;

    {
        int d0 = (t & 15) * 8;
        const float* siP = s + (size_t)bi * D_ + d0;
        float4 si0 = *(const float4*)siP;
        float4 si1 = *(const float4*)(siP + 4);
        int rbase = t >> 4;
        int pc = (t & 15) ^ (rbase & 15);
        #pragma unroll
        for (int k = 0; k < 8; ++k) {
            int row = rbase + 32 * k;
            const float* sjP = s + ((size_t)(b * N_ + row)) * D_ + d0;
            float4 a0 = *(const float4*)sjP;
            float4 a1 = *(const float4*)(sjP + 4);
            short8 v;
            v[0] = f2bfs(a0.x * si0.x); v[1] = f2bfs(a0.y * si0.y);
            v[2] = f2bfs(a0.z * si0.z); v[3] = f2bfs(a0.w * si0.w);
            v[4] = f2bfs(a1.x * si1.x); v[5] = f2bfs(a1.y * si1.y);
            v[6] = f2bfs(a1.z * si1.z); v[7] = f2bfs(a1.w * si1.w);
            *(short8*)&Pl[row * 128 + pc * 8] = v;
        }
    }
    float av[8], w2v[8];
    #pragma unroll
    for (int ni = 0; ni < 8; ++ni) {
        int h = hg * 128 + ni * 16 + l15;
        av[ni]  = avec[(size_t)bi * H_ + h];
        w2v[ni] = W2[h];
    }
    __syncthreads();

    float rsAll[4][4];
    #pragma unroll
    for (int mi = 0; mi < 4; ++mi)
        #pragma unroll
        for (int r = 0; r < 4; ++r) rsAll[mi][r] = 0.f;

    for (int half = 0; half < 2; ++half) {
        short8 Bf[4][4];
        #pragma unroll
        for (int nni = 0; nni < 4; ++nni) {
            int h = hg * 128 + half * 64 + nni * 16 + l15;
            #pragma unroll
            for (int dk = 0; dk < 4; ++dk)
                Bf[nni][dk] = *(const short8*)(Wt + (size_t)h * D_ + dk * 32 + quad * 8);
        }
        #pragma unroll 1
        for (int mi = 0; mi < 4; ++mi) {
            int jb = jg * 64 + mi * 16;
            short8 Af[4];
            #pragma unroll
            for (int dk = 0; dk < 4; ++dk) {
                int pcc = (4 * dk + quad) ^ l15;
                Af[dk] = *(const short8*)&Pl[(jb + l15) * 128 + pcc * 8];
            }
            float bv[4][4];
            #pragma unroll
            for (int nni = 0; nni < 4; ++nni) {
                int h = hg * 128 + half * 64 + nni * 16 + l15;
                #pragma unroll
                for (int r = 0; r < 4; ++r)
                    bv[nni][r] = bvec[((size_t)(b * N_ + jb + quad * 4 + r)) * H_ + h];
            }
            f32x4 acc[4];
            #pragma unroll
            for (int nni = 0; nni < 4; ++nni)
                acc[nni] = (f32x4){0.f, 0.f, 0.f, 0.f};
            #pragma unroll
            for (int dk = 0; dk < 4; ++dk)
                #pragma unroll
                for (int nni = 0; nni < 4; ++nni)
                    acc[nni] = __builtin_amdgcn_mfma_f32_16x16x32_bf16(
                        Af[dk], Bf[nni][dk], acc[nni], 0, 0, 0);
            #pragma unroll
            for (int r = 0; r < 4; ++r) {
                float rs = rsAll[mi][r];
                #pragma unroll
                for (int nni = 0; nni < 4; ++nni) {
                    int ni = half * 4 + nni;
                    float z = acc[nni][r] + av[ni] + bv[nni][r];
                    rs = fmaf(fmaxf(z, 0.f), w2v[ni], rs);
                }
                rsAll[mi][r] = rs;
            }
        }
    }
    __syncthreads();
    #pragma unroll
    for (int mi = 0; mi < 4; ++mi)
        #pragma unroll
        for (int r = 0; r < 4; ++r) {
            float v = rsAll[mi][r];
            v += __shfl_xor(v, 1); v += __shfl_xor(v, 2);
            v += __shfl_xor(v, 4); v += __shfl_xor(v, 8);
            if (l15 == 0)
                Pf[hg * 256 + jg * 64 + mi * 16 + quad * 4 + r] = v;
        }
    __syncthreads();
    if (t < 256) {
        float v = Pf[t] + Pf[256 + t] + b2[0];
        ascu[(size_t)bi * N_ + t] = f2bf(v);
    }
}

// K2 v4: same register-blocked GEMM structure as R6 (it was spill-free and
// DS-balanced) but 2 rows/block x 512 blocks x 512 threads -> 2 blocks/CU,
// 16 waves/CU (was 1 block/CU, 4 waves). Thread (pg=t&15 -> 2 pairs,
// hg=t>>4 -> 8 h), acc[2][8].
#define DCH 32
__global__ __launch_bounds__(512) void finalize_kernel(
    const float* __restrict__ s, const float* __restrict__ W1,
    const float* __restrict__ W2, const float* __restrict__ b2,
    const float* __restrict__ avec, const float* __restrict__ bvec,
    const unsigned short* __restrict__ ascu,
    float* __restrict__ ctx, float* __restrict__ gate, float* __restrict__ w)
{
    int bi0 = blockIdx.x * 2;          // 512 blocks
    int b = bi0 >> 8;
    int t = threadIdx.x;               // 0..511

    __shared__ float asc[2][N_];                    // 2 KB
    __shared__ int cand[2][16];
    __shared__ __align__(16) float Pt[D_][32];      // 16 KB [d][pair]
    __shared__ __align__(16) float Wl[DCH][H_];     // 32 KB [d-in-chunk][h]
    __shared__ float part[32][33];                  // 4.2 KB [pair][hg]
    __shared__ float rsc[2][16];
    __shared__ int sel8[2][8];

    // --- load approx scores: one element per thread ---
    {
        int tr = t >> 8, jj = t & 255;
        asc[tr][jj] = bf2f(ascu[(size_t)(bi0 + tr) * N_ + jj]);
    }
    __syncthreads();
    // --- rank-select top-16 per row (thread ranks its own (row, j)) ---
    {
        int tr = t >> 8, jj = t & 255;
        float my = asc[tr][jj];
        int rank = 0;
        #pragma unroll 8
        for (int j2 = 0; j2 < N_; ++j2) {
            float o = asc[tr][j2];
            rank += (o > my) || (o == my && j2 < jj);
        }
        if (rank < 16) cand[tr][rank] = jj;
    }
    __syncthreads();

    const float* Wc = W1 + (size_t)2 * D_ * H_;     // W1c[d][h]

    // prefetch W chunk 0
    float4 wpre[4];
    #pragma unroll
    for (int k = 0; k < 4; ++k) {
        int q = t + 512 * k;                        // 0..2047
        int dd = q >> 6, hh = (q & 63) * 4;
        wpre[k] = *(const float4*)(Wc + (size_t)dd * H_ + hh);
    }

    // build Pt[d][pair] (32 pairs)
    #pragma unroll
    for (int e = t; e < 1024; e += 512) {
        int p = e & 31, dq = e >> 5;                // dq 0..31
        int r = p >> 4, c = p & 15;
        int j = cand[r][c];
        float4 sj = *(const float4*)(s + ((size_t)(b * N_ + j)) * D_ + dq * 4);
        float4 si = *(const float4*)(s + ((size_t)(bi0 + r)) * D_ + dq * 4);
        Pt[dq * 4 + 0][p] = si.x * sj.x;
        Pt[dq * 4 + 1][p] = si.y * sj.y;
        Pt[dq * 4 + 2][p] = si.z * sj.z;
        Pt[dq * 4 + 3][p] = si.w * sj.w;
    }

    // acc init: exact fp32 a_i[h] + b_j[h]
    int pg = t & 15, hg = t >> 4;                   // hg 0..31
    int h0 = hg * 8;
    float acc[2][8];
    #pragma unroll
    for (int pp = 0; pp < 2; ++pp) {
        int p = pg * 2 + pp;
        int r = p >> 4, c = p & 15;
        int j = cand[r][c];
        const float* av = avec + (size_t)(bi0 + r) * H_ + h0;
        const float* bv = bvec + ((size_t)(b * N_ + j)) * H_ + h0;
        #pragma unroll
        for (int m4 = 0; m4 < 2; ++m4) {
            float4 a4 = *(const float4*)(av + m4 * 4);
            float4 b4 = *(const float4*)(bv + m4 * 4);
            acc[pp][m4 * 4 + 0] = a4.x + b4.x;
            acc[pp][m4 * 4 + 1] = a4.y + b4.y;
            acc[pp][m4 * 4 + 2] = a4.z + b4.z;
            acc[pp][m4 * 4 + 3] = a4.w + b4.w;
        }
    }
    __syncthreads();                                // Pt built

    // --- K-chunked GEMM: acc[pp][m] += Pt[d][2pg+pp] * W[d][h0+m] ---
    for (int ch = 0; ch < 4; ++ch) {
        #pragma unroll
        for (int k = 0; k < 4; ++k) {
            int q = t + 512 * k;
            int dd = q >> 6, hh = (q & 63) * 4;
            *(float4*)&Wl[dd][hh] = wpre[k];
        }
        __syncthreads();
        if (ch < 3) {
            int d0n = (ch + 1) * DCH;
            #pragma unroll
            for (int k = 0; k < 4; ++k) {
                int q = t + 512 * k;
                int dd = q >> 6, hh = (q & 63) * 4;
                wpre[k] = *(const float4*)(Wc + (size_t)(d0n + dd) * H_ + hh);
            }
        }
        int d0 = ch * DCH;
        #pragma unroll
        for (int d = 0; d < DCH; ++d) {
            float2 pv = *(const float2*)&Pt[d0 + d][pg * 2];
            float wv[8];
            *(float4*)&wv[0] = *(const float4*)&Wl[d][h0];
            *(float4*)&wv[4] = *(const float4*)&Wl[d][h0 + 4];
            #pragma unroll
            for (int m = 0; m < 8; ++m) {
                acc[0][m] = fmaf(pv.x, wv[m], acc[0][m]);
                acc[1][m] = fmaf(pv.y, wv[m], acc[1][m]);
            }
        }
        __syncthreads();
    }

    // --- epilogue: relu * W2, partial over this thread's 8 h ---
    {
        float w2v[8];
        *(float4*)&w2v[0] = *(const float4*)(W2 + h0);
        *(float4*)&w2v[4] = *(const float4*)(W2 + h0 + 4);
        #pragma unroll
        for (int pp = 0; pp < 2; ++pp) {
            float sc = 0.f;
            #pragma unroll
            for (int m = 0; m < 8; ++m)
                sc = fmaf(fmaxf(acc[pp][m], 0.f), w2v[m], sc);
            part[pg * 2 + pp][hg] = sc;
        }
    }
    __syncthreads();
    if (t < 32) {
        float sum = b2[0];
        #pragma unroll
        for (int m = 0; m < 32; ++m) sum += part[t][m];
        rsc[t >> 4][t & 15] = sum;
    }
    __syncthreads();

    // top-8 among 16 exact scores, tiebreak smaller original index
    if (t < 32) {
        int rr = t >> 4, cc = t & 15;
        float my = rsc[rr][cc]; int myj = cand[rr][cc];
        int rank = 0;
        #pragma unroll
        for (int c2 = 0; c2 < 16; ++c2) {
            float o = rsc[rr][c2]; int oj = cand[rr][c2];
            rank += (o > my) || (o == my && oj < myj);
        }
        if (rank < 8) sel8[rr][rank] = myj;
    }
    __syncthreads();

    // gate / w: one element per thread
    {
        int rr = t >> 8, jj = t & 255;
        float gv = 0.f;
        #pragma unroll
        for (int m = 0; m < 8; ++m)
            gv = (jj == sel8[rr][m]) ? 1.f : gv;
        gate[(size_t)(bi0 + rr) * N_ + jj] = gv;
        w[(size_t)(bi0 + rr) * N_ + jj]    = gv * 0.125f;
    }
    // ctx: 2 rows x 128 d
    if (t < 256) {
        int rr = t >> 7, d = t & 127;
        float a = 0.f;
        #pragma unroll
        for (int m = 0; m < 8; ++m)
            a += s[((size_t)(b * N_ + sel8[rr][m])) * D_ + d];
        ctx[(size_t)(bi0 + rr) * D_ + d] = a * 0.125f;
    }
}

extern "C" void kernel_launch(void* const* d_in, const int* in_sizes, int n_in,
                              void* d_out, int out_size, void* d_ws, size_t ws_size,
                              hipStream_t stream)
{
    const float* s  = (const float*)d_in[0];
    const float* W1 = (const float*)d_in[1];
    const float* b1 = (const float*)d_in[2];
    const float* W2 = (const float*)d_in[3];
    const float* b2 = (const float*)d_in[4];

    float* avec = (float*)d_ws;                                           // 262144 f
    float* bvec = avec + (size_t)B_ * N_ * H_;                            // 262144 f
    unsigned short* ascu = (unsigned short*)(bvec + (size_t)B_ * N_ * H_);// 262144 us
    unsigned short* Wtu  = ascu + (size_t)B_ * N_ * N_;                   // 32768 us

    float* ctx  = (float*)d_out;
    float* gate = ctx + (size_t)B_ * N_ * D_;
    float* wout = gate + (size_t)B_ * N_ * N_;

    pre_kernel<<<384, 256, 0, stream>>>(s, W1, b1, avec, bvec, Wtu);
    approx_scores<<<B_ * N_, 512, 0, stream>>>(s, Wtu, W2, b2, avec, bvec, ascu);
    finalize_kernel<<<B_ * N_ / 2, 512, 0, stream>>>(s, W1, W2, b2, avec, bvec, ascu,
                                                     ctx, gate, wout);
}

// Round 9
// 165.748 us; speedup vs baseline: 1.5774x; 1.0446x over previous
//
#include <hip/hip_runtime.h>
#include <hip/hip_bf16.h>
#include <math.h>

#define B_ 4
#define N_ 256
#define D_ 128
#define H_ 256
#define K_ 8

typedef __attribute__((ext_vector_type(8))) short short8;
typedef __attribute__((ext_vector_type(4))) float f32x4;

__device__ __forceinline__ unsigned short f2bf(float x) {
    union { __hip_bfloat16 h; unsigned short s; } u;
    u.h = __float2bfloat16(x);
    return u.s;
}
__device__ __forceinline__ float bf2f(unsigned short b) {
    unsigned v = ((unsigned)b) << 16;
    return __builtin_bit_cast(float, v);
}
__device__ __forceinline__ unsigned pk2(float x, float y) {
    union { __hip_bfloat162 h; unsigned u; } c;
    c.h = __float22bfloat162_rn(float2{x, y});
    return c.u;
}

// K0 (fused): blocks 0..255: avec/bvec; blocks 256..383: Wt transpose. (Unchanged.)
__global__ __launch_bounds__(256) void pre_kernel(
    const float* __restrict__ s, const float* __restrict__ W1,
    const float* __restrict__ b1,
    float* __restrict__ avec, float* __restrict__ bvec,
    unsigned short* __restrict__ Wt)
{
    int blk = blockIdx.x;
    int t = threadIdx.x;
    if (blk < 256) {
        int bi0 = blk * 4;
        __shared__ float s4[4][D_];
        for (int idx = t; idx < 4 * D_; idx += 256) {
            int r = idx >> 7, d = idx & 127;
            s4[r][d] = s[(size_t)(bi0 + r) * D_ + d];
        }
        __syncthreads();
        float aA[4], aB[4];
        float b1v = b1[t];
        #pragma unroll
        for (int r = 0; r < 4; ++r) { aA[r] = b1v; aB[r] = 0.f; }
        for (int d = 0; d < D_; ++d) {
            float wa = W1[(size_t)d * H_ + t];
            float wb = W1[(size_t)(D_ + d) * H_ + t];
            #pragma unroll
            for (int r = 0; r < 4; ++r) {
                aA[r] = fmaf(s4[r][d], wa, aA[r]);
                aB[r] = fmaf(s4[r][d], wb, aB[r]);
            }
        }
        #pragma unroll
        for (int r = 0; r < 4; ++r) {
            avec[(size_t)(bi0 + r) * H_ + t] = aA[r];
            bvec[(size_t)(bi0 + r) * H_ + t] = aB[r];
        }
    } else {
        int e = (blk - 256) * 256 + t;
        int h = e >> 7, d = e & 127;
        Wt[e] = f2bf(W1[(size_t)(2 * D_ + d) * H_ + h]);
    }
}

// K1 v3: block = (b, i, jt of 64 j), 256 thr = 4 waves (hg = 64-h slice each).
// Pl 16 KB (occupancy by VGPR, not LDS). h in 32-chunks (Bf 32 regs);
// bv double-buffered one mi ahead; a_i folded into MFMA C-init; packed
// bf16 cvt staging. Swizzle identical to R4 (measured 0 conflicts).
__global__ __launch_bounds__(256, 4) void approx_scores(
    const float* __restrict__ s, const unsigned short* __restrict__ Wt,
    const float* __restrict__ W2, const float* __restrict__ b2,
    const float* __restrict__ avec, const float* __restrict__ bvec,
    unsigned short* __restrict__ ascu)
{
    int blk = blockIdx.x;              // 4096 = bi(1024) x jt(4)
    int bi = blk >> 2;
    int jtb = (blk & 3) * 64;
    int b = bi >> 8;
    int t = threadIdx.x;
    int lane = t & 63;
    int hg = __builtin_amdgcn_readfirstlane(t >> 6);   // 0..3 -> 64-h slice
    int l15 = lane & 15, quad = lane >> 4;

    __shared__ __align__(16) short Pl[64 * 128];       // 16 KB
    float* Pf = (float*)Pl;                            // overlay after GEMM

    // --- stage P: 64 rows x 128 d, chunk-swizzled phys16B = dc ^ (row&15) ---
    {
        int dc = t & 15;
        int d0 = dc * 8;
        const float* siP = s + (size_t)bi * D_ + d0;
        float4 si0 = *(const float4*)siP;
        float4 si1 = *(const float4*)(siP + 4);
        int rbase = t >> 4;                            // 0..15
        int pc = dc ^ rbase;
        #pragma unroll
        for (int k = 0; k < 4; ++k) {
            int row = rbase + 16 * k;
            const float* sjP = s + ((size_t)(b * N_ + jtb + row)) * D_ + d0;
            float4 a0 = *(const float4*)sjP;
            float4 a1 = *(const float4*)(sjP + 4);
            uint4 v;
            v.x = pk2(a0.x * si0.x, a0.y * si0.y);
            v.y = pk2(a0.z * si0.z, a0.w * si0.w);
            v.z = pk2(a1.x * si1.x, a1.y * si1.y);
            v.w = pk2(a1.z * si1.z, a1.w * si1.w);
            *(uint4*)&Pl[row * 128 + pc * 8] = v;
        }
    }
    __syncthreads();

    float rsAll[4][4];
    #pragma unroll
    for (int mi = 0; mi < 4; ++mi)
        #pragma unroll
        for (int r = 0; r < 4; ++r) rsAll[mi][r] = 0.f;

    #pragma unroll
    for (int cc = 0; cc < 2; ++cc) {
        int h0 = hg * 64 + cc * 32;
        // W fragments for this 32-h chunk (straight from L2-resident Wt)
        short8 Bf[2][4];
        #pragma unroll
        for (int nni = 0; nni < 2; ++nni) {
            int h = h0 + nni * 16 + l15;
            #pragma unroll
            for (int dk = 0; dk < 4; ++dk)
                Bf[nni][dk] = *(const short8*)(Wt + (size_t)h * D_ + dk * 32 + quad * 8);
        }
        float avc[2], w2c[2];
        #pragma unroll
        for (int nni = 0; nni < 2; ++nni) {
            int h = h0 + nni * 16 + l15;
            avc[nni] = avec[(size_t)bi * H_ + h];
            w2c[nni] = W2[h];
        }
        // bv software pipeline: buffer for mi and mi+1
        float bv[2][2][4];
        #pragma unroll
        for (int nni = 0; nni < 2; ++nni)
            #pragma unroll
            for (int r = 0; r < 4; ++r)
                bv[0][nni][r] = bvec[((size_t)(b * N_ + jtb + quad * 4 + r)) * H_
                                     + h0 + nni * 16 + l15];
        #pragma unroll
        for (int mi = 0; mi < 4; ++mi) {
            short8 Af[4];
            #pragma unroll
            for (int dk = 0; dk < 4; ++dk) {
                int pcc = (4 * dk + quad) ^ l15;
                Af[dk] = *(const short8*)&Pl[(mi * 16 + l15) * 128 + pcc * 8];
            }
            f32x4 acc[2];
            #pragma unroll
            for (int nni = 0; nni < 2; ++nni)
                acc[nni] = (f32x4){avc[nni], avc[nni], avc[nni], avc[nni]};
            #pragma unroll
            for (int dk = 0; dk < 4; ++dk)
                #pragma unroll
                for (int nni = 0; nni < 2; ++nni)
                    acc[nni] = __builtin_amdgcn_mfma_f32_16x16x32_bf16(
                        Af[dk], Bf[nni][dk], acc[nni], 0, 0, 0);
            if (mi < 3) {   // prefetch next mi's bv (consumed next iteration)
                #pragma unroll
                for (int nni = 0; nni < 2; ++nni)
                    #pragma unroll
                    for (int r = 0; r < 4; ++r)
                        bv[(mi + 1) & 1][nni][r] =
                            bvec[((size_t)(b * N_ + jtb + (mi + 1) * 16 + quad * 4 + r)) * H_
                                 + h0 + nni * 16 + l15];
            }
            #pragma unroll
            for (int r = 0; r < 4; ++r) {
                float rs = rsAll[mi][r];
                #pragma unroll
                for (int nni = 0; nni < 2; ++nni) {
                    float z = acc[nni][r] + bv[mi & 1][nni][r];
                    rs = fmaf(fmaxf(z, 0.f), w2c[nni], rs);
                }
                rsAll[mi][r] = rs;
            }
        }
    }
    __syncthreads();                   // Pl dead; reuse as Pf
    #pragma unroll
    for (int mi = 0; mi < 4; ++mi)
        #pragma unroll
        for (int r = 0; r < 4; ++r) {
            float v = rsAll[mi][r];
            v += __shfl_xor(v, 1); v += __shfl_xor(v, 2);
            v += __shfl_xor(v, 4); v += __shfl_xor(v, 8);
            if (l15 == 0)
                Pf[hg * 64 + mi * 16 + quad * 4 + r] = v;
        }
    __syncthreads();
    if (t < 64) {
        float v = Pf[t] + Pf[64 + t] + Pf[128 + t] + Pf[192 + t] + b2[0];
        ascu[(size_t)bi * N_ + jtb + t] = f2bf(v);
    }
}

// K2 v4: (Unchanged from R7 — passed.)
#define DCH 32
__global__ __launch_bounds__(512) void finalize_kernel(
    const float* __restrict__ s, const float* __restrict__ W1,
    const float* __restrict__ W2, const float* __restrict__ b2,
    const float* __restrict__ avec, const float* __restrict__ bvec,
    const unsigned short* __restrict__ ascu,
    float* __restrict__ ctx, float* __restrict__ gate, float* __restrict__ w)
{
    int bi0 = blockIdx.x * 2;          // 512 blocks
    int b = bi0 >> 8;
    int t = threadIdx.x;               // 0..511

    __shared__ float asc[2][N_];
    __shared__ int cand[2][16];
    __shared__ __align__(16) float Pt[D_][32];
    __shared__ __align__(16) float Wl[DCH][H_];
    __shared__ float part[32][33];
    __shared__ float rsc[2][16];
    __shared__ int sel8[2][8];

    {
        int tr = t >> 8, jj = t & 255;
        asc[tr][jj] = bf2f(ascu[(size_t)(bi0 + tr) * N_ + jj]);
    }
    __syncthreads();
    {
        int tr = t >> 8, jj = t & 255;
        float my = asc[tr][jj];
        int rank = 0;
        #pragma unroll 8
        for (int j2 = 0; j2 < N_; ++j2) {
            float o = asc[tr][j2];
            rank += (o > my) || (o == my && j2 < jj);
        }
        if (rank < 16) cand[tr][rank] = jj;
    }
    __syncthreads();

    const float* Wc = W1 + (size_t)2 * D_ * H_;

    float4 wpre[4];
    #pragma unroll
    for (int k = 0; k < 4; ++k) {
        int q = t + 512 * k;
        int dd = q >> 6, hh = (q & 63) * 4;
        wpre[k] = *(const float4*)(Wc + (size_t)dd * H_ + hh);
    }

    #pragma unroll
    for (int e = t; e < 1024; e += 512) {
        int p = e & 31, dq = e >> 5;
        int r = p >> 4, c = p & 15;
        int j = cand[r][c];
        float4 sj = *(const float4*)(s + ((size_t)(b * N_ + j)) * D_ + dq * 4);
        float4 si = *(const float4*)(s + ((size_t)(bi0 + r)) * D_ + dq * 4);
        Pt[dq * 4 + 0][p] = si.x * sj.x;
        Pt[dq * 4 + 1][p] = si.y * sj.y;
        Pt[dq * 4 + 2][p] = si.z * sj.z;
        Pt[dq * 4 + 3][p] = si.w * sj.w;
    }

    int pg = t & 15, hg = t >> 4;
    int h0 = hg * 8;
    float acc[2][8];
    #pragma unroll
    for (int pp = 0; pp < 2; ++pp) {
        int p = pg * 2 + pp;
        int r = p >> 4, c = p & 15;
        int j = cand[r][c];
        const float* av = avec + (size_t)(bi0 + r) * H_ + h0;
        const float* bv = bvec + ((size_t)(b * N_ + j)) * H_ + h0;
        #pragma unroll
        for (int m4 = 0; m4 < 2; ++m4) {
            float4 a4 = *(const float4*)(av + m4 * 4);
            float4 b4 = *(const float4*)(bv + m4 * 4);
            acc[pp][m4 * 4 + 0] = a4.x + b4.x;
            acc[pp][m4 * 4 + 1] = a4.y + b4.y;
            acc[pp][m4 * 4 + 2] = a4.z + b4.z;
            acc[pp][m4 * 4 + 3] = a4.w + b4.w;
        }
    }
    __syncthreads();

    for (int ch = 0; ch < 4; ++ch) {
        #pragma unroll
        for (int k = 0; k < 4; ++k) {
            int q = t + 512 * k;
            int dd = q >> 6, hh = (q & 63) * 4;
            *(float4*)&Wl[dd][hh] = wpre[k];
        }
        __syncthreads();
        if (ch < 3) {
            int d0n = (ch + 1) * DCH;
            #pragma unroll
            for (int k = 0; k < 4; ++k) {
                int q = t + 512 * k;
                int dd = q >> 6, hh = (q & 63) * 4;
                wpre[k] = *(const float4*)(Wc + (size_t)(d0n + dd) * H_ + hh);
            }
        }
        int d0 = ch * DCH;
        #pragma unroll
        for (int d = 0; d < DCH; ++d) {
            float2 pv = *(const float2*)&Pt[d0 + d][pg * 2];
            float wv[8];
            *(float4*)&wv[0] = *(const float4*)&Wl[d][h0];
            *(float4*)&wv[4] = *(const float4*)&Wl[d][h0 + 4];
            #pragma unroll
            for (int m = 0; m < 8; ++m) {
                acc[0][m] = fmaf(pv.x, wv[m], acc[0][m]);
                acc[1][m] = fmaf(pv.y, wv[m], acc[1][m]);
            }
        }
        __syncthreads();
    }

    {
        float w2v[8];
        *(float4*)&w2v[0] = *(const float4*)(W2 + h0);
        *(float4*)&w2v[4] = *(const float4*)(W2 + h0 + 4);
        #pragma unroll
        for (int pp = 0; pp < 2; ++pp) {
            float sc = 0.f;
            #pragma unroll
            for (int m = 0; m < 8; ++m)
                sc = fmaf(fmaxf(acc[pp][m], 0.f), w2v[m], sc);
            part[pg * 2 + pp][hg] = sc;
        }
    }
    __syncthreads();
    if (t < 32) {
        float sum = b2[0];
        #pragma unroll
        for (int m = 0; m < 32; ++m) sum += part[t][m];
        rsc[t >> 4][t & 15] = sum;
    }
    __syncthreads();

    if (t < 32) {
        int rr = t >> 4, cc = t & 15;
        float my = rsc[rr][cc]; int myj = cand[rr][cc];
        int rank = 0;
        #pragma unroll
        for (int c2 = 0; c2 < 16; ++c2) {
            float o = rsc[rr][c2]; int oj = cand[rr][c2];
            rank += (o > my) || (o == my && oj < myj);
        }
        if (rank < 8) sel8[rr][rank] = myj;
    }
    __syncthreads();

    {
        int rr = t >> 8, jj = t & 255;
        float gv = 0.f;
        #pragma unroll
        for (int m = 0; m < 8; ++m)
            gv = (jj == sel8[rr][m]) ? 1.f : gv;
        gate[(size_t)(bi0 + rr) * N_ + jj] = gv;
        w[(size_t)(bi0 + rr) * N_ + jj]    = gv * 0.125f;
    }
    if (t < 256) {
        int rr = t >> 7, d = t & 127;
        float a = 0.f;
        #pragma unroll
        for (int m = 0; m < 8; ++m)
            a += s[((size_t)(b * N_ + sel8[rr][m])) * D_ + d];
        ctx[(size_t)(bi0 + rr) * D_ + d] = a * 0.125f;
    }
}

extern "C" void kernel_launch(void* const* d_in, const int* in_sizes, int n_in,
                              void* d_out, int out_size, void* d_ws, size_t ws_size,
                              hipStream_t stream)
{
    const float* s  = (const float*)d_in[0];
    const float* W1 = (const float*)d_in[1];
    const float* b1 = (const float*)d_in[2];
    const float* W2 = (const float*)d_in[3];
    const float* b2 = (const float*)d_in[4];

    float* avec = (float*)d_ws;                                           // 262144 f
    float* bvec = avec + (size_t)B_ * N_ * H_;                            // 262144 f
    unsigned short* ascu = (unsigned short*)(bvec + (size_t)B_ * N_ * H_);// 262144 us
    unsigned short* Wtu  = ascu + (size_t)B_ * N_ * N_;                   // 32768 us

    float* ctx  = (float*)d_out;
    float* gate = ctx + (size_t)B_ * N_ * D_;
    float* wout = gate + (size_t)B_ * N_ * N_;

    pre_kernel<<<384, 256, 0, stream>>>(s, W1, b1, avec, bvec, Wtu);
    approx_scores<<<B_ * N_ * 4, 256, 0, stream>>>(s, Wtu, W2, b2, avec, bvec, ascu);
    finalize_kernel<<<B_ * N_ / 2, 512, 0, stream>>>(s, W1, W2, b2, avec, bvec, ascu,
                                                     ctx, gate, wout);
}